// Round 10
// baseline (211.948 us; speedup 1.0000x reference)
//
#include <hip/hip_runtime.h>
#include <stdint.h>

#define S_LEN 2048
#define BATCH 2
#define HID 2048
#define NH 16
#define NKV 8
#define HD 128
#define WINDOW 1024
#define SCALE 0.08838834764831845f
#define QKVW 4096

typedef unsigned short u16;
typedef unsigned int u32;
typedef __attribute__((ext_vector_type(8))) short short8;
typedef __attribute__((ext_vector_type(4))) float f32x4;
typedef __attribute__((ext_vector_type(16))) float f32x16;
typedef __attribute__((ext_vector_type(4))) u16 u16x4;

__device__ __forceinline__ u16 f2b(float f) {
  u32 u = __builtin_bit_cast(u32, f);
  return (u16)((u + 0x7fffu + ((u >> 16) & 1u)) >> 16);
}
__device__ __forceinline__ float b2f(u16 h) {
  u32 u = ((u32)h) << 16;
  return __builtin_bit_cast(float, u);
}
__device__ __forceinline__ u32 pk_bf16(float a, float b) {
  u32 d;
  asm("v_cvt_pk_bf16_f32 %0, %1, %2" : "=v"(d) : "v"(a), "v"(b));
  return d;
}

__device__ __forceinline__ void gload_lds16(const u16* g, u16* l) {
  __builtin_amdgcn_global_load_lds(
      (const __attribute__((address_space(1))) u32*)g,
      (__attribute__((address_space(3))) u32*)l, 16, 0, 0);
}

template <int N>
__device__ __forceinline__ void wait_vm() {
  if constexpr (N == 0) asm volatile("s_waitcnt vmcnt(0)" ::: "memory");
  else if constexpr (N == 6) asm volatile("s_waitcnt vmcnt(6)" ::: "memory");
  else if constexpr (N == 8) asm volatile("s_waitcnt vmcnt(8)" ::: "memory");
}

// ---------------- f32 -> bf16 convert ----------------
__global__ __launch_bounds__(256) void k_conv(const float* __restrict__ src,
                                              u16* __restrict__ dst, int n4) {
  int i = blockIdx.x * blockDim.x + threadIdx.x;
  int st = gridDim.x * blockDim.x;
  for (; i < n4; i += st) {
    f32x4 v = ((const f32x4*)src)[i];
    u16x4 o;
    o[0] = f2b(v[0]); o[1] = f2b(v[1]); o[2] = f2b(v[2]); o[3] = f2b(v[3]);
    ((u16x4*)dst)[i] = o;
  }
}

__device__ __forceinline__ void store_c(u16* C, long idx, float v) { C[idx] = f2b(v); }
__device__ __forceinline__ void store_c(float* C, long idx, float v) { C[idx] = v; }

// ---- GEMM C = A*B^T : 128x256 block, 4 waves of 128x64, BK=32, 2 blocks/CU --
// Round-10 fix: chunk swizzle ch ^ ((row ^ (row>>2)) & 3). With 64-B rows the
// old (row>>2)-only swizzle was constant over 4 consecutive rows -> 4 lanes
// per (parity,chunk) bank-slot per 16-lane group -> 4-way conflict (6.3M
// measured). New swizzle: lanes 0-15 hit all 8 slots exactly twice (round-8's
// proven conflict-free density). Read-side lane constant: (l15^(l15>>2))&3.
// Staging source inverse-swizzled, LDS dst linear (rule 21).
template <typename OutT>
__global__ __launch_bounds__(256, 2) void k_gemmW(const u16* __restrict__ A,
                                                  const u16* __restrict__ B,
                                                  OutT* __restrict__ C,
                                                  int M, int N, int K) {
  __shared__ u16 sA[2][128 * 32];   // 8 KB per buf
  __shared__ u16 sB[2][256 * 32];   // 16 KB per buf  -> 48 KB total
  const int tid = threadIdx.x;
  const int lane = tid & 63;
  const int w = tid >> 6;           // wave = n-quadrant (0..3)
  const int l15 = lane & 15;
  const int lg = lane >> 4;

  const int gx = gridDim.x;                 // N / 256
  const int nwg = gx * gridDim.y;
  const int flat = blockIdx.y * gx + blockIdx.x;
  const int tile = (flat & 7) * (nwg >> 3) + (flat >> 3);
  const long m0 = (long)(tile / gx) * 128;
  const long n0 = (long)(tile % gx) * 256;

  const u16* Abase = A + m0 * K;
  const u16* Bbase = B + n0 * K;

  // staging: 16B chunks; chunk c -> row = c>>2, ch = c&3 (rows are 64B)
  // global source chunk = ch ^ ((row ^ (row>>2)) & 3)
  int aOff[2], aDst[2], bOff[4], bDst[4];
#pragma unroll
  for (int i = 0; i < 2; ++i) {
    const int c = tid + i * 256;            // 512 A-chunks
    const int row = c >> 2, ch = c & 3;
    aOff[i] = row * K + (ch ^ ((row ^ (row >> 2)) & 3)) * 8;
    aDst[i] = c * 8;
  }
#pragma unroll
  for (int i = 0; i < 4; ++i) {
    const int c = tid + i * 256;            // 1024 B-chunks
    const int row = c >> 2, ch = c & 3;
    bOff[i] = row * K + (ch ^ ((row ^ (row >> 2)) & 3)) * 8;
    bDst[i] = c * 8;
  }

  f32x4 acc[8][4];
  const f32x4 z4 = {0.f, 0.f, 0.f, 0.f};
#pragma unroll
  for (int i = 0; i < 8; ++i)
#pragma unroll
    for (int j = 0; j < 4; ++j) acc[i][j] = z4;

  // fragment read: row = base16 + l15 -> (row ^ (row>>2))&3 = (l15 ^ (l15>>2))&3
  const int chsw = (lg ^ ((l15 ^ (l15 >> 2)) & 3)) * 8;
  const int brow0 = w * 64;

  const int NT = K >> 5;            // BK = 32

#define STG(KT, BUF)                                                    \
  _Pragma("unroll") for (int i_ = 0; i_ < 2; ++i_)                      \
      gload_lds16(Abase + aOff[i_] + (KT) * 32, &sA[BUF][aDst[i_]]);    \
  _Pragma("unroll") for (int i_ = 0; i_ < 4; ++i_)                      \
      gload_lds16(Bbase + bOff[i_] + (KT) * 32, &sB[BUF][bDst[i_]]);

  STG(0, 0)                         // prologue

  for (int t = 0; t < NT; ++t) {
    const int cur = t & 1;
    if (t + 1 < NT) {
      STG(t + 1, cur ^ 1)
      wait_vm<6>();                 // drain tile t, leave t+1's 6 loads in flight
    } else {
      wait_vm<0>();
    }
    __builtin_amdgcn_sched_barrier(0);
    __builtin_amdgcn_s_barrier();
    __builtin_amdgcn_sched_barrier(0);

    short8 af[8], bf[4];
#pragma unroll
    for (int i = 0; i < 8; ++i)
      af[i] = *(const short8*)&sA[cur][(i * 16 + l15) * 32 + chsw];
#pragma unroll
    for (int j = 0; j < 4; ++j)
      bf[j] = *(const short8*)&sB[cur][(brow0 + j * 16 + l15) * 32 + chsw];
    __builtin_amdgcn_s_setprio(1);
#pragma unroll
    for (int i = 0; i < 8; ++i)
#pragma unroll
      for (int j = 0; j < 4; ++j)
        acc[i][j] = __builtin_amdgcn_mfma_f32_16x16x32_bf16(
            af[i], bf[j], acc[i][j], 0, 0, 0);
    __builtin_amdgcn_s_setprio(0);

    __builtin_amdgcn_s_barrier();
    __builtin_amdgcn_sched_barrier(0);
  }
#undef STG

#pragma unroll
  for (int i = 0; i < 8; ++i)
#pragma unroll
    for (int j = 0; j < 4; ++j)
#pragma unroll
      for (int r = 0; r < 4; ++r) {
        long row = m0 + i * 16 + lg * 4 + r;
        long col = n0 + w * 64 + j * 16 + l15;
        store_c(C, row * (long)N + col, acc[i][j][r]);
      }
}

// ---- GEMM (round-8 structure, kept for Wo) : 128x128, BK=64, 2 blocks/CU ----
template <typename OutT>
__global__ __launch_bounds__(256, 2) void k_gemm2b(const u16* __restrict__ A,
                                                   const u16* __restrict__ B,
                                                   OutT* __restrict__ C,
                                                   int M, int N, int K) {
  __shared__ u16 sA[2][128 * 64];
  __shared__ u16 sB[2][128 * 64];
  const int tid = threadIdx.x;
  const int lane = tid & 63;
  const int w = tid >> 6;
  const int l15 = lane & 15;
  const int lg = lane >> 4;
  const int wm = w >> 1;
  const int wn = w & 1;
  const int sw = l15 & 7;

  const int gx = gridDim.x;
  const int nwg = gx * gridDim.y;
  const int flat = blockIdx.y * gx + blockIdx.x;
  const int tile = (flat & 7) * (nwg >> 3) + (flat >> 3);
  const long m0 = (long)(tile / gx) * 128;
  const long n0 = (long)(tile % gx) * 128;

  const u16* Abase = A + m0 * K;
  const u16* Bbase = B + n0 * K;

  int aOff[4], bOff[4], dstOff[4];
#pragma unroll
  for (int i = 0; i < 4; ++i) {
    const int c = tid + i * 256;
    const int row = c >> 3, chs = c & 7;
    const int scol = (chs ^ (row & 7)) * 8;
    aOff[i] = row * K + scol;
    bOff[i] = row * K + scol;
    dstOff[i] = c * 8;
  }

  f32x4 acc[4][4];
  const f32x4 z4 = {0.f, 0.f, 0.f, 0.f};
#pragma unroll
  for (int i = 0; i < 4; ++i)
#pragma unroll
    for (int j = 0; j < 4; ++j) acc[i][j] = z4;

  const int arow = (wm * 64 + l15) * 64;
  const int brow = (wn * 64 + l15) * 64;
  const int akc0 = (lg ^ sw) * 8;
  const int akc1 = ((4 + lg) ^ sw) * 8;

  const int NT = K >> 6;

#define STG(KT, BUF)                                                     \
  _Pragma("unroll") for (int i_ = 0; i_ < 4; ++i_)                       \
      gload_lds16(Abase + aOff[i_] + (KT) * 64, &sA[BUF][dstOff[i_]]);   \
  _Pragma("unroll") for (int i_ = 0; i_ < 4; ++i_)                       \
      gload_lds16(Bbase + bOff[i_] + (KT) * 64, &sB[BUF][dstOff[i_]]);

  STG(0, 0)

  for (int t = 0; t < NT; ++t) {
    const int cur = t & 1;
    if (t + 1 < NT) {
      STG(t + 1, cur ^ 1)
      wait_vm<8>();
    } else {
      wait_vm<0>();
    }
    __builtin_amdgcn_sched_barrier(0);
    __builtin_amdgcn_s_barrier();
    __builtin_amdgcn_sched_barrier(0);

#pragma unroll
    for (int kk = 0; kk < 2; ++kk) {
      const int akc = (kk == 0) ? akc0 : akc1;
      short8 afk[4], bfk[4];
#pragma unroll
      for (int i = 0; i < 4; ++i)
        afk[i] = *(const short8*)&sA[cur][arow + i * 16 * 64 + akc];
#pragma unroll
      for (int j = 0; j < 4; ++j)
        bfk[j] = *(const short8*)&sB[cur][brow + j * 16 * 64 + akc];
      __builtin_amdgcn_s_setprio(1);
#pragma unroll
      for (int i = 0; i < 4; ++i)
#pragma unroll
        for (int j = 0; j < 4; ++j)
          acc[i][j] = __builtin_amdgcn_mfma_f32_16x16x32_bf16(
              afk[i], bfk[j], acc[i][j], 0, 0, 0);
      __builtin_amdgcn_s_setprio(0);
    }
    __builtin_amdgcn_s_barrier();
    __builtin_amdgcn_sched_barrier(0);
  }
#undef STG

#pragma unroll
  for (int i = 0; i < 4; ++i)
#pragma unroll
    for (int j = 0; j < 4; ++j)
#pragma unroll
      for (int r = 0; r < 4; ++r) {
        long row = m0 + wm * 64 + i * 16 + lg * 4 + r;
        long col = n0 + wn * 64 + j * 16 + l15;
        store_c(C, row * (long)N + col, acc[i][j][r]);
      }
}

// ---------------- RMSNorm + RoPE (in place on fused QKV, bf16) ----------------
__global__ __launch_bounds__(256) void k_normrope(u16* __restrict__ QKV,
                                                  const float* __restrict__ cosb,
                                                  const float* __restrict__ sinb,
                                                  const float* __restrict__ qw,
                                                  const float* __restrict__ kw) {
  const int lane = threadIdx.x & 63;
  const int w = threadIdx.x >> 6;
  int row = blockIdx.x * 4 + w;
  const int nQ = BATCH * S_LEN * NH;
  u16* p;
  const float* nw;
  int tok;
  float sc;
  if (row < nQ) {
    tok = row >> 4;
    int h = row & 15;
    p = QKV + (long)tok * QKVW + h * HD;
    nw = qw;
    sc = SCALE;
  } else {
    int r2 = row - nQ;
    tok = r2 >> 3;
    int h = r2 & 7;
    p = QKV + (long)tok * QKVW + 2048 + h * HD;
    nw = kw;
    sc = 1.0f;
  }
  float x0 = b2f(p[lane]);
  float x1 = b2f(p[lane + 64]);
  float ss = x0 * x0 + x1 * x1;
#pragma unroll
  for (int mk = 1; mk < 64; mk <<= 1) ss += __shfl_xor(ss, mk, 64);
  float rinv = rsqrtf(ss * (1.0f / 128.0f) + 1e-6f);
  float y0 = x0 * rinv * nw[lane];
  float y1 = x1 * rinv * nw[lane + 64];
  const float* cp = cosb + (long)tok * HD;
  const float* sp = sinb + (long)tok * HD;
  float o0 = (y0 * cp[lane] - y1 * sp[lane]) * sc;
  float o1 = (y1 * cp[lane + 64] + y0 * sp[lane + 64]) * sc;
  p[lane] = f2b(o0);
  p[lane + 64] = f2b(o1);
}

// ---------------- Flash attention (unchanged) ----------------
__global__ __launch_bounds__(256, 2) void k_attn(const u16* __restrict__ QKV,
                                                 u16* __restrict__ AO) {
  __shared__ u16 sK[64 * 128];
  __shared__ u16 sVT[64 * 128];
  const int tid = threadIdx.x;
  const int lane = tid & 63;
  const int l31 = lane & 31;
  const int hi = lane >> 5;
  const int w = tid >> 6;
  const int q0 = blockIdx.x * 128;
  const int h = blockIdx.y;
  const int b = blockIdx.z;
  const int kvh = h >> 1;
  const int qw0 = q0 + w * 32;
  const int iq = qw0 + l31;

  const long tokbase = (long)b * S_LEN;
  const u16* Qrow = QKV + (tokbase + qw0 + l31) * QKVW + h * HD;
  short8 qf[8];
#pragma unroll
  for (int dt = 0; dt < 8; ++dt) qf[dt] = *(const short8*)(Qrow + dt * 16 + hi * 8);

  f32x16 o[4];
#pragma unroll
  for (int n = 0; n < 4; ++n)
#pragma unroll
    for (int r = 0; r < 16; ++r) o[n][r] = 0.f;
  float m = 0.f, lsum = 0.f;

  const u16* Kbase = QKV + tokbase * QKVW + 2048 + kvh * HD;
  const u16* Vbase = QKV + tokbase * QKVW + 3072 + kvh * HD;

  int kc_row[4], kc_off[4];
  u16* kc_dst[4];
#pragma unroll
  for (int i = 0; i < 4; ++i) {
    const int c = tid + 256 * i;
    kc_row[i] = c >> 4;
    kc_off[i] = (((c & 15) ^ ((c >> 4) & 7))) * 8;
    kc_dst[i] = &sK[c * 8];
  }
  const int rp = tid & 31;
  const int dc0 = tid >> 5;
  const int rg_st = rp >> 2;

  int t_lo = q0 - (WINDOW - 1);
  t_lo = (t_lo < 0 ? 0 : t_lo) >> 6;
  const int t_hi = (q0 + 127) >> 6;

  for (int t = t_lo; t <= t_hi; ++t) {
    const int kv0 = t << 6;
#pragma unroll
    for (int i = 0; i < 4; ++i)
      gload_lds16(Kbase + (long)(kv0 + kc_row[i]) * QKVW + kc_off[i], kc_dst[i]);
#pragma unroll
    for (int i = 0; i < 2; ++i) {
      const int dc = dc0 + i * 8;
      const u16* vp = Vbase + (long)(kv0 + 2 * rp) * QKVW + dc * 8;
      short8 v0 = *(const short8*)vp;
      short8 v1 = *(const short8*)(vp + QKVW);
#pragma unroll
      for (int e = 0; e < 8; ++e) {
        const int d = dc * 8 + e;
        const int unit = d * 8 + (rg_st ^ (d & 7));
        ((u32*)sVT)[unit * 4 + (rp & 3)] = (u32)(u16)v0[e] | ((u32)(u16)v1[e] << 16);
      }
    }
    __syncthreads();

    const bool skipw = (kv0 > qw0 + 31) || (kv0 + 63 < qw0 - (WINDOW - 1));
    if (!skipw) {
      const bool full = (kv0 + 63 <= qw0) && ((qw0 + 31) - kv0 < WINDOW);
      f32x16 s0, s1;
#pragma unroll
      for (int r = 0; r < 16; ++r) { s0[r] = 0.f; s1[r] = 0.f; }
      const int rsw = l31 & 7;
#pragma unroll
      for (int dt = 0; dt < 8; ++dt) {
        const int ch = hi + 2 * dt;
        const short8 kf0 = *(const short8*)&sK[(l31 * 16 + (ch ^ rsw)) * 8];
        s0 = __builtin_amdgcn_mfma_f32_32x32x16_bf16(kf0, qf[dt], s0, 0, 0, 0);
        const short8 kf1 = *(const short8*)&sK[((l31 + 32) * 16 + (ch ^ rsw)) * 8];
        s1 = __builtin_amdgcn_mfma_f32_32x32x16_bf16(kf1, qf[dt], s1, 0, 0, 0);
      }
      float p[32];
#pragma unroll
      for (int r = 0; r < 16; ++r) { p[r] = s0[r]; p[16 + r] = s1[r]; }
      if (!full) {
#pragma unroll
        for (int r = 0; r < 32; ++r) {
          const int kk = kv0 + (r >> 4) * 32 + 4 * hi + (r & 3) + 8 * ((r >> 2) & 3);
          p[r] = ((u32)(iq - kk) < (u32)WINDOW) ? p[r] : -3.0e38f;
        }
      }
      float tm = p[0];
#pragma unroll
      for (int r = 1; r < 32; ++r) tm = fmaxf(tm, p[r]);
      tm = fmaxf(tm, __shfl_xor(tm, 32, 64));
      const float mn = fmaxf(m, tm);
      const float al = __expf(m - mn);
      m = mn;
      float rs = 0.f;
#pragma unroll
      for (int r = 0; r < 32; ++r) { p[r] = __expf(p[r] - mn); rs += p[r]; }
      rs += __shfl_xor(rs, 32, 64);
      lsum = lsum * al + rs;
#pragma unroll
      for (int n = 0; n < 4; ++n)
#pragma unroll
        for (int r = 0; r < 16; ++r) o[n][r] *= al;

      short8 pf[4];
#pragma unroll
      for (int ks = 0; ks < 4; ++ks) {
        const int bb = (ks >> 1) * 16 + (ks & 1) * 8;
        u32 a0 = pk_bf16(p[bb + 0], p[bb + 1]);
        u32 b0 = pk_bf16(p[bb + 4], p[bb + 5]);
        u32 a1 = pk_bf16(p[bb + 2], p[bb + 3]);
        u32 b1 = pk_bf16(p[bb + 6], p[bb + 7]);
        asm volatile("v_permlane32_swap_b32 %0, %1" : "+v"(a0), "+v"(b0));
        asm volatile("v_permlane32_swap_b32 %0, %1" : "+v"(a1), "+v"(b1));
        union { u32 u[4]; short8 s; } uu;
        uu.u[0] = a0; uu.u[1] = a1; uu.u[2] = b0; uu.u[3] = b1;
        pf[ks] = uu.s;
      }
#pragma unroll
      for (int dt = 0; dt < 4; ++dt) {
        const int d = l31 + 32 * dt;
        const int dsw = d & 7;
#pragma unroll
        for (int ks = 0; ks < 4; ++ks) {
          const int rg = ks * 2 + hi;
          const short8 vf = *(const short8*)&sVT[(d * 8 + (rg ^ dsw)) * 8];
          o[dt] = __builtin_amdgcn_mfma_f32_32x32x16_bf16(vf, pf[ks], o[dt], 0, 0, 0);
        }
      }
    }
    __syncthreads();
  }

  __syncthreads();
  float* R = ((float*)sK) + w * 1024;
  const float rl = 1.0f / lsum;
  const int half = hi;
#pragma unroll
  for (int dt = 0; dt < 4; ++dt) {
#pragma unroll
    for (int r = 0; r < 16; ++r) {
      const int dp = 4 * hi + (r & 3) + 8 * (r >> 2);
      R[dp * 32 + (l31 ^ (4 * (dp & 7)))] = o[dt][r] * rl;
    }
    __syncthreads();
    union { u16 hh[16]; short8 s[2]; } U;
#pragma unroll
    for (int j = 0; j < 16; ++j) {
      const int dp = half * 16 + j;
      U.hh[j] = f2b(R[dp * 32 + (l31 ^ (4 * (dp & 7)))]);
    }
    u16* dst = AO + (tokbase + q0 + w * 32 + l31) * (NH * HD) + h * HD + dt * 32 + half * 16;
    *(short8*)dst = U.s[0];
    *(short8*)(dst + 8) = U.s[1];
    __syncthreads();
  }
}

// ---------------- launch ----------------
extern "C" void kernel_launch(void* const* d_in, const int* in_sizes, int n_in,
                              void* d_out, int out_size, void* d_ws, size_t ws_size,
                              hipStream_t stream) {
  const float* hs   = (const float*)d_in[0];
  const float* cosb = (const float*)d_in[1];
  const float* sinb = (const float*)d_in[2];
  const float* Wq   = (const float*)d_in[3];
  const float* Wk   = (const float*)d_in[4];
  const float* Wv   = (const float*)d_in[5];
  const float* Wo   = (const float*)d_in[6];
  const float* qw   = (const float*)d_in[7];
  const float* kw   = (const float*)d_in[8];
  float* out = (float*)d_out;

  const long SZ_X  = (long)BATCH * S_LEN * HID;
  const long SZ_WQ = (long)NH * HD * HID;
  const long SZ_WK = (long)NKV * HD * HID;
  u16* Xb   = (u16*)d_ws;
  u16* Wqb  = Xb + SZ_X;
  u16* Wkb  = Wqb + SZ_WQ;
  u16* Wvb  = Wkb + SZ_WK;
  u16* Wob  = Wvb + SZ_WK;
  u16* QKVb = Wob + SZ_WQ;
  u16* AOb  = QKVb + (long)BATCH * S_LEN * QKVW;

  k_conv<<<2048, 256, 0, stream>>>(hs, Xb, (int)(SZ_X / 4));
  k_conv<<<1024, 256, 0, stream>>>(Wq, Wqb, (int)(SZ_WQ / 4));
  k_conv<<<512, 256, 0, stream>>>(Wk, Wkb, (int)(SZ_WK / 4));
  k_conv<<<512, 256, 0, stream>>>(Wv, Wvb, (int)(SZ_WK / 4));
  k_conv<<<1024, 256, 0, stream>>>(Wo, Wob, (int)(SZ_WQ / 4));

  // fused QKV projection: 4096 x 4096 x 2048
  // k_gemmW: 128x256 tiles -> 16 x 32 = 512 blocks (2/CU)
  k_gemmW<u16><<<dim3(16, 32), 256, 0, stream>>>(
      Xb, Wqb, QKVb, BATCH * S_LEN, QKVW, HID);

  k_normrope<<<(BATCH * S_LEN * (NH + NKV)) / 4, 256, 0, stream>>>(QKVb, cosb, sinb, qw, kw);

  k_attn<<<dim3(S_LEN / 128, NH, BATCH), 256, 0, stream>>>(QKVb, AOb);

  // output projection: 4096 x 2048 x 2048, 128x128 tiles, 512 blocks (2/CU)
  k_gemm2b<float><<<dim3(16, 32), 256, 0, stream>>>(
      AOb, Wob, out, BATCH * S_LEN, HID, HID);
}

// Round 11
// 208.981 us; speedup vs baseline: 1.0142x; 1.0142x over previous
//
#include <hip/hip_runtime.h>
#include <stdint.h>

#define S_LEN 2048
#define BATCH 2
#define HID 2048
#define NH 16
#define NKV 8
#define HD 128
#define WINDOW 1024
#define SCALE 0.08838834764831845f
#define QKVW 4096

typedef unsigned short u16;
typedef unsigned int u32;
typedef __attribute__((ext_vector_type(8))) short short8;
typedef __attribute__((ext_vector_type(4))) float f32x4;
typedef __attribute__((ext_vector_type(16))) float f32x16;
typedef __attribute__((ext_vector_type(4))) u16 u16x4;

__device__ __forceinline__ u16 f2b(float f) {
  u32 u = __builtin_bit_cast(u32, f);
  return (u16)((u + 0x7fffu + ((u >> 16) & 1u)) >> 16);
}
__device__ __forceinline__ float b2f(u16 h) {
  u32 u = ((u32)h) << 16;
  return __builtin_bit_cast(float, u);
}
__device__ __forceinline__ u32 pk_bf16(float a, float b) {
  u32 d;
  asm("v_cvt_pk_bf16_f32 %0, %1, %2" : "=v"(d) : "v"(a), "v"(b));
  return d;
}

__device__ __forceinline__ void gload_lds16(const u16* g, u16* l) {
  __builtin_amdgcn_global_load_lds(
      (const __attribute__((address_space(1))) u32*)g,
      (__attribute__((address_space(3))) u32*)l, 16, 0, 0);
}

template <int N>
__device__ __forceinline__ void wait_vm() {
  if constexpr (N == 0) asm volatile("s_waitcnt vmcnt(0)" ::: "memory");
}

// ---------------- fused f32 -> bf16 convert (5 segments, 1 launch) ----------
// dst layout is contiguous: Xb | Wqb | Wkb | Wvb | Wob  (f32x4 quad units)
#define CQ0 2097152   // X     : 8M  elems = 2M quads
#define CQ1 3145728   // + Wq  : 4M  = 1M quads
#define CQ2 3670016   // + Wk  : 2M  = 0.5M
#define CQ3 4194304   // + Wv  : 2M  = 0.5M
#define CQ4 5242880   // + Wo  : 4M  = 1M
__global__ __launch_bounds__(256) void k_conv5(const float* __restrict__ s0,
                                               const float* __restrict__ s1,
                                               const float* __restrict__ s2,
                                               const float* __restrict__ s3,
                                               const float* __restrict__ s4,
                                               u16* __restrict__ dst) {
  int i = blockIdx.x * blockDim.x + threadIdx.x;
  const int st = gridDim.x * blockDim.x;
  for (; i < CQ4; i += st) {
    const f32x4* src;
    if (i < CQ0)      src = (const f32x4*)s0 + i;
    else if (i < CQ1) src = (const f32x4*)s1 + (i - CQ0);
    else if (i < CQ2) src = (const f32x4*)s2 + (i - CQ1);
    else if (i < CQ3) src = (const f32x4*)s3 + (i - CQ2);
    else              src = (const f32x4*)s4 + (i - CQ3);
    f32x4 v = *src;
    u16x4 o;
    o[0] = f2b(v[0]); o[1] = f2b(v[1]); o[2] = f2b(v[2]); o[3] = f2b(v[3]);
    ((u16x4*)dst)[i] = o;
  }
}

__device__ __forceinline__ void store_c(u16* C, long idx, float v) { C[idx] = f2b(v); }
__device__ __forceinline__ void store_c(float* C, long idx, float v) { C[idx] = v; }

// ---- GEMM C = A*B^T : 128x128 tile, BK=64, SINGLE-buffer, 4 blocks/CU ------
// Occupancy play: 32 KB LDS + launch_bounds(256,4) -> 4 blocks/CU = 16
// waves/CU (vs 8 in every prior round). While one block drains vmcnt(0),
// up to 3 other blocks feed the MFMA pipe (m114 cross-block overlap; m97's
// mechanism). Layout = round-8's empirically zero-conflict one: 128B rows,
// chunk = (kk*4+lg) ^ (l15&7), staging source inverse-swizzled, LDS linear.
template <typename OutT>
__global__ __launch_bounds__(256, 4) void k_gemmS(const u16* __restrict__ A,
                                                  const u16* __restrict__ B,
                                                  OutT* __restrict__ C,
                                                  int M, int N, int K) {
  __shared__ u16 sA[128 * 64];   // 16 KB
  __shared__ u16 sB[128 * 64];   // 16 KB
  const int tid = threadIdx.x;
  const int lane = tid & 63;
  const int w = tid >> 6;
  const int l15 = lane & 15;
  const int lg = lane >> 4;
  const int wm = w >> 1;
  const int wn = w & 1;
  const int sw = l15 & 7;

  const int gx = gridDim.x;
  const int nwg = gx * gridDim.y;
  const int flat = blockIdx.y * gx + blockIdx.x;
  const int tile = (flat & 7) * (nwg >> 3) + (flat >> 3);
  const long m0 = (long)(tile / gx) * 128;
  const long n0 = (long)(tile % gx) * 128;

  const u16* Abase = A + m0 * K;
  const u16* Bbase = B + n0 * K;

  // 1024 16B chunks per matrix per K-tile; 4 A + 4 B per thread.
  int aOff[4], bOff[4], dstOff[4];
#pragma unroll
  for (int i = 0; i < 4; ++i) {
    const int c = tid + i * 256;
    const int row = c >> 3, chs = c & 7;
    const int scol = (chs ^ (row & 7)) * 8;
    aOff[i] = row * K + scol;
    bOff[i] = row * K + scol;
    dstOff[i] = c * 8;
  }

  f32x4 acc[4][4];
  const f32x4 z4 = {0.f, 0.f, 0.f, 0.f};
#pragma unroll
  for (int i = 0; i < 4; ++i)
#pragma unroll
    for (int j = 0; j < 4; ++j) acc[i][j] = z4;

  const int arow = (wm * 64 + l15) * 64;
  const int brow = (wn * 64 + l15) * 64;
  const int akc0 = (lg ^ sw) * 8;
  const int akc1 = ((4 + lg) ^ sw) * 8;

  const int NT = K >> 6;

  for (int t = 0; t < NT; ++t) {
#pragma unroll
    for (int i = 0; i < 4; ++i)
      gload_lds16(Abase + aOff[i] + t * 64, &sA[dstOff[i]]);
#pragma unroll
    for (int i = 0; i < 4; ++i)
      gload_lds16(Bbase + bOff[i] + t * 64, &sB[dstOff[i]]);
    wait_vm<0>();
    __builtin_amdgcn_sched_barrier(0);
    __builtin_amdgcn_s_barrier();
    __builtin_amdgcn_sched_barrier(0);

#pragma unroll
    for (int kk = 0; kk < 2; ++kk) {
      const int akc = (kk == 0) ? akc0 : akc1;
      short8 afk[4], bfk[4];
#pragma unroll
      for (int i = 0; i < 4; ++i)
        afk[i] = *(const short8*)&sA[arow + i * 16 * 64 + akc];
#pragma unroll
      for (int j = 0; j < 4; ++j)
        bfk[j] = *(const short8*)&sB[brow + j * 16 * 64 + akc];
      __builtin_amdgcn_s_setprio(1);
#pragma unroll
      for (int i = 0; i < 4; ++i)
#pragma unroll
        for (int j = 0; j < 4; ++j)
          acc[i][j] = __builtin_amdgcn_mfma_f32_16x16x32_bf16(
              afk[i], bfk[j], acc[i][j], 0, 0, 0);
      __builtin_amdgcn_s_setprio(0);
    }
    __builtin_amdgcn_s_barrier();      // all reads of tile t done before restage
    __builtin_amdgcn_sched_barrier(0);
  }

#pragma unroll
  for (int i = 0; i < 4; ++i)
#pragma unroll
    for (int j = 0; j < 4; ++j)
#pragma unroll
      for (int r = 0; r < 4; ++r) {
        long row = m0 + wm * 64 + i * 16 + lg * 4 + r;
        long col = n0 + wn * 64 + j * 16 + l15;
        store_c(C, row * (long)N + col, acc[i][j][r]);
      }
}

// ---------------- RMSNorm + RoPE (in place on fused QKV, bf16) ----------------
__global__ __launch_bounds__(256) void k_normrope(u16* __restrict__ QKV,
                                                  const float* __restrict__ cosb,
                                                  const float* __restrict__ sinb,
                                                  const float* __restrict__ qw,
                                                  const float* __restrict__ kw) {
  const int lane = threadIdx.x & 63;
  const int w = threadIdx.x >> 6;
  int row = blockIdx.x * 4 + w;
  const int nQ = BATCH * S_LEN * NH;
  u16* p;
  const float* nw;
  int tok;
  float sc;
  if (row < nQ) {
    tok = row >> 4;
    int h = row & 15;
    p = QKV + (long)tok * QKVW + h * HD;
    nw = qw;
    sc = SCALE;
  } else {
    int r2 = row - nQ;
    tok = r2 >> 3;
    int h = r2 & 7;
    p = QKV + (long)tok * QKVW + 2048 + h * HD;
    nw = kw;
    sc = 1.0f;
  }
  float x0 = b2f(p[lane]);
  float x1 = b2f(p[lane + 64]);
  float ss = x0 * x0 + x1 * x1;
#pragma unroll
  for (int mk = 1; mk < 64; mk <<= 1) ss += __shfl_xor(ss, mk, 64);
  float rinv = rsqrtf(ss * (1.0f / 128.0f) + 1e-6f);
  float y0 = x0 * rinv * nw[lane];
  float y1 = x1 * rinv * nw[lane + 64];
  const float* cp = cosb + (long)tok * HD;
  const float* sp = sinb + (long)tok * HD;
  float o0 = (y0 * cp[lane] - y1 * sp[lane]) * sc;
  float o1 = (y1 * cp[lane + 64] + y0 * sp[lane + 64]) * sc;
  p[lane] = f2b(o0);
  p[lane + 64] = f2b(o1);
}

// ---------------- Flash attention (unchanged) ----------------
__global__ __launch_bounds__(256, 2) void k_attn(const u16* __restrict__ QKV,
                                                 u16* __restrict__ AO) {
  __shared__ u16 sK[64 * 128];
  __shared__ u16 sVT[64 * 128];
  const int tid = threadIdx.x;
  const int lane = tid & 63;
  const int l31 = lane & 31;
  const int hi = lane >> 5;
  const int w = tid >> 6;
  const int q0 = blockIdx.x * 128;
  const int h = blockIdx.y;
  const int b = blockIdx.z;
  const int kvh = h >> 1;
  const int qw0 = q0 + w * 32;
  const int iq = qw0 + l31;

  const long tokbase = (long)b * S_LEN;
  const u16* Qrow = QKV + (tokbase + qw0 + l31) * QKVW + h * HD;
  short8 qf[8];
#pragma unroll
  for (int dt = 0; dt < 8; ++dt) qf[dt] = *(const short8*)(Qrow + dt * 16 + hi * 8);

  f32x16 o[4];
#pragma unroll
  for (int n = 0; n < 4; ++n)
#pragma unroll
    for (int r = 0; r < 16; ++r) o[n][r] = 0.f;
  float m = 0.f, lsum = 0.f;

  const u16* Kbase = QKV + tokbase * QKVW + 2048 + kvh * HD;
  const u16* Vbase = QKV + tokbase * QKVW + 3072 + kvh * HD;

  int kc_row[4], kc_off[4];
  u16* kc_dst[4];
#pragma unroll
  for (int i = 0; i < 4; ++i) {
    const int c = tid + 256 * i;
    kc_row[i] = c >> 4;
    kc_off[i] = (((c & 15) ^ ((c >> 4) & 7))) * 8;
    kc_dst[i] = &sK[c * 8];
  }
  const int rp = tid & 31;
  const int dc0 = tid >> 5;
  const int rg_st = rp >> 2;

  int t_lo = q0 - (WINDOW - 1);
  t_lo = (t_lo < 0 ? 0 : t_lo) >> 6;
  const int t_hi = (q0 + 127) >> 6;

  for (int t = t_lo; t <= t_hi; ++t) {
    const int kv0 = t << 6;
#pragma unroll
    for (int i = 0; i < 4; ++i)
      gload_lds16(Kbase + (long)(kv0 + kc_row[i]) * QKVW + kc_off[i], kc_dst[i]);
#pragma unroll
    for (int i = 0; i < 2; ++i) {
      const int dc = dc0 + i * 8;
      const u16* vp = Vbase + (long)(kv0 + 2 * rp) * QKVW + dc * 8;
      short8 v0 = *(const short8*)vp;
      short8 v1 = *(const short8*)(vp + QKVW);
#pragma unroll
      for (int e = 0; e < 8; ++e) {
        const int d = dc * 8 + e;
        const int unit = d * 8 + (rg_st ^ (d & 7));
        ((u32*)sVT)[unit * 4 + (rp & 3)] = (u32)(u16)v0[e] | ((u32)(u16)v1[e] << 16);
      }
    }
    __syncthreads();

    const bool skipw = (kv0 > qw0 + 31) || (kv0 + 63 < qw0 - (WINDOW - 1));
    if (!skipw) {
      const bool full = (kv0 + 63 <= qw0) && ((qw0 + 31) - kv0 < WINDOW);
      f32x16 s0, s1;
#pragma unroll
      for (int r = 0; r < 16; ++r) { s0[r] = 0.f; s1[r] = 0.f; }
      const int rsw = l31 & 7;
#pragma unroll
      for (int dt = 0; dt < 8; ++dt) {
        const int ch = hi + 2 * dt;
        const short8 kf0 = *(const short8*)&sK[(l31 * 16 + (ch ^ rsw)) * 8];
        s0 = __builtin_amdgcn_mfma_f32_32x32x16_bf16(kf0, qf[dt], s0, 0, 0, 0);
        const short8 kf1 = *(const short8*)&sK[((l31 + 32) * 16 + (ch ^ rsw)) * 8];
        s1 = __builtin_amdgcn_mfma_f32_32x32x16_bf16(kf1, qf[dt], s1, 0, 0, 0);
      }
      float p[32];
#pragma unroll
      for (int r = 0; r < 16; ++r) { p[r] = s0[r]; p[16 + r] = s1[r]; }
      if (!full) {
#pragma unroll
        for (int r = 0; r < 32; ++r) {
          const int kk = kv0 + (r >> 4) * 32 + 4 * hi + (r & 3) + 8 * ((r >> 2) & 3);
          p[r] = ((u32)(iq - kk) < (u32)WINDOW) ? p[r] : -3.0e38f;
        }
      }
      float tm = p[0];
#pragma unroll
      for (int r = 1; r < 32; ++r) tm = fmaxf(tm, p[r]);
      tm = fmaxf(tm, __shfl_xor(tm, 32, 64));
      const float mn = fmaxf(m, tm);
      const float al = __expf(m - mn);
      m = mn;
      float rs = 0.f;
#pragma unroll
      for (int r = 0; r < 32; ++r) { p[r] = __expf(p[r] - mn); rs += p[r]; }
      rs += __shfl_xor(rs, 32, 64);
      lsum = lsum * al + rs;
#pragma unroll
      for (int n = 0; n < 4; ++n)
#pragma unroll
        for (int r = 0; r < 16; ++r) o[n][r] *= al;

      short8 pf[4];
#pragma unroll
      for (int ks = 0; ks < 4; ++ks) {
        const int bb = (ks >> 1) * 16 + (ks & 1) * 8;
        u32 a0 = pk_bf16(p[bb + 0], p[bb + 1]);
        u32 b0 = pk_bf16(p[bb + 4], p[bb + 5]);
        u32 a1 = pk_bf16(p[bb + 2], p[bb + 3]);
        u32 b1 = pk_bf16(p[bb + 6], p[bb + 7]);
        asm volatile("v_permlane32_swap_b32 %0, %1" : "+v"(a0), "+v"(b0));
        asm volatile("v_permlane32_swap_b32 %0, %1" : "+v"(a1), "+v"(b1));
        union { u32 u[4]; short8 s; } uu;
        uu.u[0] = a0; uu.u[1] = a1; uu.u[2] = b0; uu.u[3] = b1;
        pf[ks] = uu.s;
      }
#pragma unroll
      for (int dt = 0; dt < 4; ++dt) {
        const int d = l31 + 32 * dt;
        const int dsw = d & 7;
#pragma unroll
        for (int ks = 0; ks < 4; ++ks) {
          const int rg = ks * 2 + hi;
          const short8 vf = *(const short8*)&sVT[(d * 8 + (rg ^ dsw)) * 8];
          o[dt] = __builtin_amdgcn_mfma_f32_32x32x16_bf16(vf, pf[ks], o[dt], 0, 0, 0);
        }
      }
    }
    __syncthreads();
  }

  __syncthreads();
  float* R = ((float*)sK) + w * 1024;
  const float rl = 1.0f / lsum;
  const int half = hi;
#pragma unroll
  for (int dt = 0; dt < 4; ++dt) {
#pragma unroll
    for (int r = 0; r < 16; ++r) {
      const int dp = 4 * hi + (r & 3) + 8 * (r >> 2);
      R[dp * 32 + (l31 ^ (4 * (dp & 7)))] = o[dt][r] * rl;
    }
    __syncthreads();
    union { u16 hh[16]; short8 s[2]; } U;
#pragma unroll
    for (int j = 0; j < 16; ++j) {
      const int dp = half * 16 + j;
      U.hh[j] = f2b(R[dp * 32 + (l31 ^ (4 * (dp & 7)))]);
    }
    u16* dst = AO + (tokbase + q0 + w * 32 + l31) * (NH * HD) + h * HD + dt * 32 + half * 16;
    *(short8*)dst = U.s[0];
    *(short8*)(dst + 8) = U.s[1];
    __syncthreads();
  }
}

// ---------------- launch ----------------
extern "C" void kernel_launch(void* const* d_in, const int* in_sizes, int n_in,
                              void* d_out, int out_size, void* d_ws, size_t ws_size,
                              hipStream_t stream) {
  const float* hs   = (const float*)d_in[0];
  const float* cosb = (const float*)d_in[1];
  const float* sinb = (const float*)d_in[2];
  const float* Wq   = (const float*)d_in[3];
  const float* Wk   = (const float*)d_in[4];
  const float* Wv   = (const float*)d_in[5];
  const float* Wo   = (const float*)d_in[6];
  const float* qw   = (const float*)d_in[7];
  const float* kw   = (const float*)d_in[8];
  float* out = (float*)d_out;

  const long SZ_X  = (long)BATCH * S_LEN * HID;
  const long SZ_WQ = (long)NH * HD * HID;
  const long SZ_WK = (long)NKV * HD * HID;
  u16* Xb   = (u16*)d_ws;
  u16* Wqb  = Xb + SZ_X;
  u16* Wkb  = Wqb + SZ_WQ;
  u16* Wvb  = Wkb + SZ_WK;
  u16* Wob  = Wvb + SZ_WK;
  u16* QKVb = Wob + SZ_WQ;
  u16* AOb  = QKVb + (long)BATCH * S_LEN * QKVW;

  // one fused convert launch (dst = Xb|Wqb|Wkb|Wvb|Wob contiguous)
  k_conv5<<<2048, 256, 0, stream>>>(hs, Wq, Wk, Wv, Wo, Xb);

  // fused QKV projection: 4096 x 4096 x 2048, 1024 blocks (4/CU resident)
  k_gemmS<u16><<<dim3(32, 32), 256, 0, stream>>>(
      Xb, Wqb, QKVb, BATCH * S_LEN, QKVW, HID);

  k_normrope<<<(BATCH * S_LEN * (NH + NKV)) / 4, 256, 0, stream>>>(QKVb, cosb, sinb, qw, kw);

  k_attn<<<dim3(S_LEN / 128, NH, BATCH), 256, 0, stream>>>(QKVb, AOb);

  // output projection: 4096 x 2048 x 2048, 512 blocks
  k_gemmS<float><<<dim3(16, 32), 256, 0, stream>>>(
      AOb, Wob, out, BATCH * S_LEN, HID, HID);
}

// Round 12
// 203.218 us; speedup vs baseline: 1.0430x; 1.0284x over previous
//
#include <hip/hip_runtime.h>
#include <stdint.h>

#define S_LEN 2048
#define BATCH 2
#define HID 2048
#define NH 16
#define NKV 8
#define HD 128
#define WINDOW 1024
#define SCALE 0.08838834764831845f
#define QKVW 4096

typedef unsigned short u16;
typedef unsigned int u32;
typedef __attribute__((ext_vector_type(8))) short short8;
typedef __attribute__((ext_vector_type(4))) float f32x4;
typedef __attribute__((ext_vector_type(16))) float f32x16;
typedef __attribute__((ext_vector_type(4))) u16 u16x4;

__device__ __forceinline__ u16 f2b(float f) {
  u32 u = __builtin_bit_cast(u32, f);
  return (u16)((u + 0x7fffu + ((u >> 16) & 1u)) >> 16);
}
__device__ __forceinline__ float b2f(u16 h) {
  u32 u = ((u32)h) << 16;
  return __builtin_bit_cast(float, u);
}
__device__ __forceinline__ u32 pk_bf16(float a, float b) {
  u32 d;
  asm("v_cvt_pk_bf16_f32 %0, %1, %2" : "=v"(d) : "v"(a), "v"(b));
  return d;
}

__device__ __forceinline__ void gload_lds16(const u16* g, u16* l) {
  __builtin_amdgcn_global_load_lds(
      (const __attribute__((address_space(1))) u32*)g,
      (__attribute__((address_space(3))) u32*)l, 16, 0, 0);
}

template <int N>
__device__ __forceinline__ void wait_vm() {
  if constexpr (N == 0) asm volatile("s_waitcnt vmcnt(0)" ::: "memory");
}

// ---------------- fused f32 -> bf16 convert (5 segments, 1 launch) ----------
#define CQ0 2097152
#define CQ1 3145728
#define CQ2 3670016
#define CQ3 4194304
#define CQ4 5242880
__global__ __launch_bounds__(256) void k_conv5(const float* __restrict__ s0,
                                               const float* __restrict__ s1,
                                               const float* __restrict__ s2,
                                               const float* __restrict__ s3,
                                               const float* __restrict__ s4,
                                               u16* __restrict__ dst) {
  int i = blockIdx.x * blockDim.x + threadIdx.x;
  const int st = gridDim.x * blockDim.x;
  for (; i < CQ4; i += st) {
    const f32x4* src;
    if (i < CQ0)      src = (const f32x4*)s0 + i;
    else if (i < CQ1) src = (const f32x4*)s1 + (i - CQ0);
    else if (i < CQ2) src = (const f32x4*)s2 + (i - CQ1);
    else if (i < CQ3) src = (const f32x4*)s3 + (i - CQ2);
    else              src = (const f32x4*)s4 + (i - CQ3);
    f32x4 v = *src;
    u16x4 o;
    o[0] = f2b(v[0]); o[1] = f2b(v[1]); o[2] = f2b(v[2]); o[3] = f2b(v[3]);
    ((u16x4*)dst)[i] = o;
  }
}

__device__ __forceinline__ void store_c(u16* C, long idx, float v) { C[idx] = f2b(v); }
__device__ __forceinline__ void store_c(float* C, long idx, float v) { C[idx] = v; }

// ---- GEMM C = A*B^T : 128x128 tile, 2 waves of 128x64, BK=64, 4 blocks/CU --
// Traffic-ratio play: per-wave 128x64 output cuts LDS fragment reads from
// 512 to 375 B/MFMA (block: 80 KB reads + 32 KB writes per 128 MFMA = 640
// B/MFMA -> ~49% ceiling vs round-11's 768 B/MFMA -> 40%, measured 41.5%).
// Same proven zero-conflict layout + single-buffer vmcnt(0) structure as
// round 11; 128 threads, launch_bounds(128,2) -> 4 blocks/CU, 8 waves/CU.
template <typename OutT>
__global__ __launch_bounds__(128, 2) void k_gemmV(const u16* __restrict__ A,
                                                  const u16* __restrict__ B,
                                                  OutT* __restrict__ C,
                                                  int M, int N, int K) {
  __shared__ u16 sA[128 * 64];   // 16 KB
  __shared__ u16 sB[128 * 64];   // 16 KB
  const int tid = threadIdx.x;
  const int lane = tid & 63;
  const int w = tid >> 6;        // wave = n-half (0..1)
  const int l15 = lane & 15;
  const int lg = lane >> 4;
  const int sw = l15 & 7;

  const int gx = gridDim.x;
  const int nwg = gx * gridDim.y;
  const int flat = blockIdx.y * gx + blockIdx.x;
  const int tile = (flat & 7) * (nwg >> 3) + (flat >> 3);
  const long m0 = (long)(tile / gx) * 128;
  const long n0 = (long)(tile % gx) * 128;

  const u16* Abase = A + m0 * K;
  const u16* Bbase = B + n0 * K;

  // 1024 16B chunks per matrix per K-tile; 8 A + 8 B per thread (128 thr).
  int aOff[8], dstOff[8];
#pragma unroll
  for (int i = 0; i < 8; ++i) {
    const int c = tid + i * 128;
    const int row = c >> 3, chs = c & 7;
    aOff[i] = row * K + (chs ^ (row & 7)) * 8;
    dstOff[i] = c * 8;
  }

  f32x4 acc[8][4];
  const f32x4 z4 = {0.f, 0.f, 0.f, 0.f};
#pragma unroll
  for (int i = 0; i < 8; ++i)
#pragma unroll
    for (int j = 0; j < 4; ++j) acc[i][j] = z4;

  const int akc0 = (lg ^ sw) * 8;
  const int akc1 = ((4 + lg) ^ sw) * 8;
  const int brow0 = w * 64;

  const int NT = K >> 6;

  for (int t = 0; t < NT; ++t) {
#pragma unroll
    for (int i = 0; i < 8; ++i)
      gload_lds16(Abase + aOff[i] + t * 64, &sA[dstOff[i]]);
#pragma unroll
    for (int i = 0; i < 8; ++i)
      gload_lds16(Bbase + aOff[i] + t * 64, &sB[dstOff[i]]);
    wait_vm<0>();
    __builtin_amdgcn_sched_barrier(0);
    __builtin_amdgcn_s_barrier();
    __builtin_amdgcn_sched_barrier(0);

#pragma unroll
    for (int kk = 0; kk < 2; ++kk) {
      const int akc = (kk == 0) ? akc0 : akc1;
      short8 afk[8], bfk[4];
#pragma unroll
      for (int i = 0; i < 8; ++i)
        afk[i] = *(const short8*)&sA[(i * 16 + l15) * 64 + akc];
#pragma unroll
      for (int j = 0; j < 4; ++j)
        bfk[j] = *(const short8*)&sB[(brow0 + j * 16 + l15) * 64 + akc];
      __builtin_amdgcn_s_setprio(1);
#pragma unroll
      for (int i = 0; i < 8; ++i)
#pragma unroll
        for (int j = 0; j < 4; ++j)
          acc[i][j] = __builtin_amdgcn_mfma_f32_16x16x32_bf16(
              afk[i], bfk[j], acc[i][j], 0, 0, 0);
      __builtin_amdgcn_s_setprio(0);
    }
    __builtin_amdgcn_s_barrier();
    __builtin_amdgcn_sched_barrier(0);
  }

#pragma unroll
  for (int i = 0; i < 8; ++i)
#pragma unroll
    for (int j = 0; j < 4; ++j)
#pragma unroll
      for (int r = 0; r < 4; ++r) {
        long row = m0 + i * 16 + lg * 4 + r;
        long col = n0 + w * 64 + j * 16 + l15;
        store_c(C, row * (long)N + col, acc[i][j][r]);
      }
}

// ---- GEMM (round-11 structure, kept for Wo) : 128x128, 4 waves, 4/CU -------
template <typename OutT>
__global__ __launch_bounds__(256, 4) void k_gemmS(const u16* __restrict__ A,
                                                  const u16* __restrict__ B,
                                                  OutT* __restrict__ C,
                                                  int M, int N, int K) {
  __shared__ u16 sA[128 * 64];
  __shared__ u16 sB[128 * 64];
  const int tid = threadIdx.x;
  const int lane = tid & 63;
  const int w = tid >> 6;
  const int l15 = lane & 15;
  const int lg = lane >> 4;
  const int wm = w >> 1;
  const int wn = w & 1;
  const int sw = l15 & 7;

  const int gx = gridDim.x;
  const int nwg = gx * gridDim.y;
  const int flat = blockIdx.y * gx + blockIdx.x;
  const int tile = (flat & 7) * (nwg >> 3) + (flat >> 3);
  const long m0 = (long)(tile / gx) * 128;
  const long n0 = (long)(tile % gx) * 128;

  const u16* Abase = A + m0 * K;
  const u16* Bbase = B + n0 * K;

  int aOff[4], dstOff[4];
#pragma unroll
  for (int i = 0; i < 4; ++i) {
    const int c = tid + i * 256;
    const int row = c >> 3, chs = c & 7;
    aOff[i] = row * K + (chs ^ (row & 7)) * 8;
    dstOff[i] = c * 8;
  }

  f32x4 acc[4][4];
  const f32x4 z4 = {0.f, 0.f, 0.f, 0.f};
#pragma unroll
  for (int i = 0; i < 4; ++i)
#pragma unroll
    for (int j = 0; j < 4; ++j) acc[i][j] = z4;

  const int arow = (wm * 64 + l15) * 64;
  const int brow = (wn * 64 + l15) * 64;
  const int akc0 = (lg ^ sw) * 8;
  const int akc1 = ((4 + lg) ^ sw) * 8;

  const int NT = K >> 6;

  for (int t = 0; t < NT; ++t) {
#pragma unroll
    for (int i = 0; i < 4; ++i)
      gload_lds16(Abase + aOff[i] + t * 64, &sA[dstOff[i]]);
#pragma unroll
    for (int i = 0; i < 4; ++i)
      gload_lds16(Bbase + aOff[i] + t * 64, &sB[dstOff[i]]);
    wait_vm<0>();
    __builtin_amdgcn_sched_barrier(0);
    __builtin_amdgcn_s_barrier();
    __builtin_amdgcn_sched_barrier(0);

#pragma unroll
    for (int kk = 0; kk < 2; ++kk) {
      const int akc = (kk == 0) ? akc0 : akc1;
      short8 afk[4], bfk[4];
#pragma unroll
      for (int i = 0; i < 4; ++i)
        afk[i] = *(const short8*)&sA[arow + i * 16 * 64 + akc];
#pragma unroll
      for (int j = 0; j < 4; ++j)
        bfk[j] = *(const short8*)&sB[brow + j * 16 * 64 + akc];
      __builtin_amdgcn_s_setprio(1);
#pragma unroll
      for (int i = 0; i < 4; ++i)
#pragma unroll
        for (int j = 0; j < 4; ++j)
          acc[i][j] = __builtin_amdgcn_mfma_f32_16x16x32_bf16(
              afk[i], bfk[j], acc[i][j], 0, 0, 0);
      __builtin_amdgcn_s_setprio(0);
    }
    __builtin_amdgcn_s_barrier();
    __builtin_amdgcn_sched_barrier(0);
  }

#pragma unroll
  for (int i = 0; i < 4; ++i)
#pragma unroll
    for (int j = 0; j < 4; ++j)
#pragma unroll
      for (int r = 0; r < 4; ++r) {
        long row = m0 + wm * 64 + i * 16 + lg * 4 + r;
        long col = n0 + wn * 64 + j * 16 + l15;
        store_c(C, row * (long)N + col, acc[i][j][r]);
      }
}

// ---------------- RMSNorm + RoPE (in place on fused QKV, bf16) ----------------
__global__ __launch_bounds__(256) void k_normrope(u16* __restrict__ QKV,
                                                  const float* __restrict__ cosb,
                                                  const float* __restrict__ sinb,
                                                  const float* __restrict__ qw,
                                                  const float* __restrict__ kw) {
  const int lane = threadIdx.x & 63;
  const int w = threadIdx.x >> 6;
  int row = blockIdx.x * 4 + w;
  const int nQ = BATCH * S_LEN * NH;
  u16* p;
  const float* nw;
  int tok;
  float sc;
  if (row < nQ) {
    tok = row >> 4;
    int h = row & 15;
    p = QKV + (long)tok * QKVW + h * HD;
    nw = qw;
    sc = SCALE;
  } else {
    int r2 = row - nQ;
    tok = r2 >> 3;
    int h = r2 & 7;
    p = QKV + (long)tok * QKVW + 2048 + h * HD;
    nw = kw;
    sc = 1.0f;
  }
  float x0 = b2f(p[lane]);
  float x1 = b2f(p[lane + 64]);
  float ss = x0 * x0 + x1 * x1;
#pragma unroll
  for (int mk = 1; mk < 64; mk <<= 1) ss += __shfl_xor(ss, mk, 64);
  float rinv = rsqrtf(ss * (1.0f / 128.0f) + 1e-6f);
  float y0 = x0 * rinv * nw[lane];
  float y1 = x1 * rinv * nw[lane + 64];
  const float* cp = cosb + (long)tok * HD;
  const float* sp = sinb + (long)tok * HD;
  float o0 = (y0 * cp[lane] - y1 * sp[lane]) * sc;
  float o1 = (y1 * cp[lane + 64] + y0 * sp[lane + 64]) * sc;
  p[lane] = f2b(o0);
  p[lane + 64] = f2b(o1);
}

// ---------------- Flash attention (unchanged) ----------------
__global__ __launch_bounds__(256, 2) void k_attn(const u16* __restrict__ QKV,
                                                 u16* __restrict__ AO) {
  __shared__ u16 sK[64 * 128];
  __shared__ u16 sVT[64 * 128];
  const int tid = threadIdx.x;
  const int lane = tid & 63;
  const int l31 = lane & 31;
  const int hi = lane >> 5;
  const int w = tid >> 6;
  const int q0 = blockIdx.x * 128;
  const int h = blockIdx.y;
  const int b = blockIdx.z;
  const int kvh = h >> 1;
  const int qw0 = q0 + w * 32;
  const int iq = qw0 + l31;

  const long tokbase = (long)b * S_LEN;
  const u16* Qrow = QKV + (tokbase + qw0 + l31) * QKVW + h * HD;
  short8 qf[8];
#pragma unroll
  for (int dt = 0; dt < 8; ++dt) qf[dt] = *(const short8*)(Qrow + dt * 16 + hi * 8);

  f32x16 o[4];
#pragma unroll
  for (int n = 0; n < 4; ++n)
#pragma unroll
    for (int r = 0; r < 16; ++r) o[n][r] = 0.f;
  float m = 0.f, lsum = 0.f;

  const u16* Kbase = QKV + tokbase * QKVW + 2048 + kvh * HD;
  const u16* Vbase = QKV + tokbase * QKVW + 3072 + kvh * HD;

  int kc_row[4], kc_off[4];
  u16* kc_dst[4];
#pragma unroll
  for (int i = 0; i < 4; ++i) {
    const int c = tid + 256 * i;
    kc_row[i] = c >> 4;
    kc_off[i] = (((c & 15) ^ ((c >> 4) & 7))) * 8;
    kc_dst[i] = &sK[c * 8];
  }
  const int rp = tid & 31;
  const int dc0 = tid >> 5;
  const int rg_st = rp >> 2;

  int t_lo = q0 - (WINDOW - 1);
  t_lo = (t_lo < 0 ? 0 : t_lo) >> 6;
  const int t_hi = (q0 + 127) >> 6;

  for (int t = t_lo; t <= t_hi; ++t) {
    const int kv0 = t << 6;
#pragma unroll
    for (int i = 0; i < 4; ++i)
      gload_lds16(Kbase + (long)(kv0 + kc_row[i]) * QKVW + kc_off[i], kc_dst[i]);
#pragma unroll
    for (int i = 0; i < 2; ++i) {
      const int dc = dc0 + i * 8;
      const u16* vp = Vbase + (long)(kv0 + 2 * rp) * QKVW + dc * 8;
      short8 v0 = *(const short8*)vp;
      short8 v1 = *(const short8*)(vp + QKVW);
#pragma unroll
      for (int e = 0; e < 8; ++e) {
        const int d = dc * 8 + e;
        const int unit = d * 8 + (rg_st ^ (d & 7));
        ((u32*)sVT)[unit * 4 + (rp & 3)] = (u32)(u16)v0[e] | ((u32)(u16)v1[e] << 16);
      }
    }
    __syncthreads();

    const bool skipw = (kv0 > qw0 + 31) || (kv0 + 63 < qw0 - (WINDOW - 1));
    if (!skipw) {
      const bool full = (kv0 + 63 <= qw0) && ((qw0 + 31) - kv0 < WINDOW);
      f32x16 s0, s1;
#pragma unroll
      for (int r = 0; r < 16; ++r) { s0[r] = 0.f; s1[r] = 0.f; }
      const int rsw = l31 & 7;
#pragma unroll
      for (int dt = 0; dt < 8; ++dt) {
        const int ch = hi + 2 * dt;
        const short8 kf0 = *(const short8*)&sK[(l31 * 16 + (ch ^ rsw)) * 8];
        s0 = __builtin_amdgcn_mfma_f32_32x32x16_bf16(kf0, qf[dt], s0, 0, 0, 0);
        const short8 kf1 = *(const short8*)&sK[((l31 + 32) * 16 + (ch ^ rsw)) * 8];
        s1 = __builtin_amdgcn_mfma_f32_32x32x16_bf16(kf1, qf[dt], s1, 0, 0, 0);
      }
      float p[32];
#pragma unroll
      for (int r = 0; r < 16; ++r) { p[r] = s0[r]; p[16 + r] = s1[r]; }
      if (!full) {
#pragma unroll
        for (int r = 0; r < 32; ++r) {
          const int kk = kv0 + (r >> 4) * 32 + 4 * hi + (r & 3) + 8 * ((r >> 2) & 3);
          p[r] = ((u32)(iq - kk) < (u32)WINDOW) ? p[r] : -3.0e38f;
        }
      }
      float tm = p[0];
#pragma unroll
      for (int r = 1; r < 32; ++r) tm = fmaxf(tm, p[r]);
      tm = fmaxf(tm, __shfl_xor(tm, 32, 64));
      const float mn = fmaxf(m, tm);
      const float al = __expf(m - mn);
      m = mn;
      float rs = 0.f;
#pragma unroll
      for (int r = 0; r < 32; ++r) { p[r] = __expf(p[r] - mn); rs += p[r]; }
      rs += __shfl_xor(rs, 32, 64);
      lsum = lsum * al + rs;
#pragma unroll
      for (int n = 0; n < 4; ++n)
#pragma unroll
        for (int r = 0; r < 16; ++r) o[n][r] *= al;

      short8 pf[4];
#pragma unroll
      for (int ks = 0; ks < 4; ++ks) {
        const int bb = (ks >> 1) * 16 + (ks & 1) * 8;
        u32 a0 = pk_bf16(p[bb + 0], p[bb + 1]);
        u32 b0 = pk_bf16(p[bb + 4], p[bb + 5]);
        u32 a1 = pk_bf16(p[bb + 2], p[bb + 3]);
        u32 b1 = pk_bf16(p[bb + 6], p[bb + 7]);
        asm volatile("v_permlane32_swap_b32 %0, %1" : "+v"(a0), "+v"(b0));
        asm volatile("v_permlane32_swap_b32 %0, %1" : "+v"(a1), "+v"(b1));
        union { u32 u[4]; short8 s; } uu;
        uu.u[0] = a0; uu.u[1] = a1; uu.u[2] = b0; uu.u[3] = b1;
        pf[ks] = uu.s;
      }
#pragma unroll
      for (int dt = 0; dt < 4; ++dt) {
        const int d = l31 + 32 * dt;
        const int dsw = d & 7;
#pragma unroll
        for (int ks = 0; ks < 4; ++ks) {
          const int rg = ks * 2 + hi;
          const short8 vf = *(const short8*)&sVT[(d * 8 + (rg ^ dsw)) * 8];
          o[dt] = __builtin_amdgcn_mfma_f32_32x32x16_bf16(vf, pf[ks], o[dt], 0, 0, 0);
        }
      }
    }
    __syncthreads();
  }

  __syncthreads();
  float* R = ((float*)sK) + w * 1024;
  const float rl = 1.0f / lsum;
  const int half = hi;
#pragma unroll
  for (int dt = 0; dt < 4; ++dt) {
#pragma unroll
    for (int r = 0; r < 16; ++r) {
      const int dp = 4 * hi + (r & 3) + 8 * (r >> 2);
      R[dp * 32 + (l31 ^ (4 * (dp & 7)))] = o[dt][r] * rl;
    }
    __syncthreads();
    union { u16 hh[16]; short8 s[2]; } U;
#pragma unroll
    for (int j = 0; j < 16; ++j) {
      const int dp = half * 16 + j;
      U.hh[j] = f2b(R[dp * 32 + (l31 ^ (4 * (dp & 7)))]);
    }
    u16* dst = AO + (tokbase + q0 + w * 32 + l31) * (NH * HD) + h * HD + dt * 32 + half * 16;
    *(short8*)dst = U.s[0];
    *(short8*)(dst + 8) = U.s[1];
    __syncthreads();
  }
}

// ---------------- launch ----------------
extern "C" void kernel_launch(void* const* d_in, const int* in_sizes, int n_in,
                              void* d_out, int out_size, void* d_ws, size_t ws_size,
                              hipStream_t stream) {
  const float* hs   = (const float*)d_in[0];
  const float* cosb = (const float*)d_in[1];
  const float* sinb = (const float*)d_in[2];
  const float* Wq   = (const float*)d_in[3];
  const float* Wk   = (const float*)d_in[4];
  const float* Wv   = (const float*)d_in[5];
  const float* Wo   = (const float*)d_in[6];
  const float* qw   = (const float*)d_in[7];
  const float* kw   = (const float*)d_in[8];
  float* out = (float*)d_out;

  const long SZ_X  = (long)BATCH * S_LEN * HID;
  const long SZ_WQ = (long)NH * HD * HID;
  const long SZ_WK = (long)NKV * HD * HID;
  u16* Xb   = (u16*)d_ws;
  u16* Wqb  = Xb + SZ_X;
  u16* Wkb  = Wqb + SZ_WQ;
  u16* Wvb  = Wkb + SZ_WK;
  u16* Wob  = Wvb + SZ_WK;
  u16* QKVb = Wob + SZ_WQ;
  u16* AOb  = QKVb + (long)BATCH * S_LEN * QKVW;

  k_conv5<<<2048, 256, 0, stream>>>(hs, Wq, Wk, Wv, Wo, Xb);

  // fused QKV projection: 4096 x 4096 x 2048, 1024 blocks of 128 thr (4/CU)
  k_gemmV<u16><<<dim3(32, 32), 128, 0, stream>>>(
      Xb, Wqb, QKVb, BATCH * S_LEN, QKVW, HID);

  k_normrope<<<(BATCH * S_LEN * (NH + NKV)) / 4, 256, 0, stream>>>(QKVb, cosb, sinb, qw, kw);

  k_attn<<<dim3(S_LEN / 128, NH, BATCH), 256, 0, stream>>>(QKVb, AOb);

  // output projection: 4096 x 2048 x 2048, 512 blocks (round-11 kernel)
  k_gemmS<float><<<dim3(16, 32), 256, 0, stream>>>(
      AOb, Wob, out, BATCH * S_LEN, HID, HID);
}

// Round 13
// 195.754 us; speedup vs baseline: 1.0827x; 1.0381x over previous
//
#include <hip/hip_runtime.h>
#include <stdint.h>

#define S_LEN 2048
#define BATCH 2
#define HID 2048
#define NH 16
#define NKV 8
#define HD 128
#define WINDOW 1024
#define SCALE 0.08838834764831845f
#define QKVW 4096

typedef unsigned short u16;
typedef unsigned int u32;
typedef __attribute__((ext_vector_type(8))) short short8;
typedef __attribute__((ext_vector_type(4))) float f32x4;
typedef __attribute__((ext_vector_type(16))) float f32x16;
typedef __attribute__((ext_vector_type(4))) u16 u16x4;

__device__ __forceinline__ u16 f2b(float f) {
  u32 u = __builtin_bit_cast(u32, f);
  return (u16)((u + 0x7fffu + ((u >> 16) & 1u)) >> 16);
}
__device__ __forceinline__ float b2f(u16 h) {
  u32 u = ((u32)h) << 16;
  return __builtin_bit_cast(float, u);
}
__device__ __forceinline__ u32 pk_bf16(float a, float b) {
  u32 d;
  asm("v_cvt_pk_bf16_f32 %0, %1, %2" : "=v"(d) : "v"(a), "v"(b));
  return d;
}

__device__ __forceinline__ void gload_lds16(const u16* g, u16* l) {
  __builtin_amdgcn_global_load_lds(
      (const __attribute__((address_space(1))) u32*)g,
      (__attribute__((address_space(3))) u32*)l, 16, 0, 0);
}

template <int N>
__device__ __forceinline__ void wait_vm() {
  if constexpr (N == 0) asm volatile("s_waitcnt vmcnt(0)" ::: "memory");
}

// ---------------- fused f32 -> bf16 convert (5 segments, 1 launch) ----------
#define CQ0 2097152
#define CQ1 3145728
#define CQ2 3670016
#define CQ3 4194304
#define CQ4 5242880
__global__ __launch_bounds__(256) void k_conv5(const float* __restrict__ s0,
                                               const float* __restrict__ s1,
                                               const float* __restrict__ s2,
                                               const float* __restrict__ s3,
                                               const float* __restrict__ s4,
                                               u16* __restrict__ dst) {
  int i = blockIdx.x * blockDim.x + threadIdx.x;
  const int st = gridDim.x * blockDim.x;
  for (; i < CQ4; i += st) {
    const f32x4* src;
    if (i < CQ0)      src = (const f32x4*)s0 + i;
    else if (i < CQ1) src = (const f32x4*)s1 + (i - CQ0);
    else if (i < CQ2) src = (const f32x4*)s2 + (i - CQ1);
    else if (i < CQ3) src = (const f32x4*)s3 + (i - CQ2);
    else              src = (const f32x4*)s4 + (i - CQ3);
    f32x4 v = *src;
    u16x4 o;
    o[0] = f2b(v[0]); o[1] = f2b(v[1]); o[2] = f2b(v[2]); o[3] = f2b(v[3]);
    ((u16x4*)dst)[i] = o;
  }
}

__device__ __forceinline__ void store_c(u16* C, long idx, float v) { C[idx] = f2b(v); }
__device__ __forceinline__ void store_c(float* C, long idx, float v) { C[idx] = v; }

// ---- GEMM C = A*B^T : 128x256 tile, 4 waves of 128x64, BK=64, 2 blocks/CU --
// Two-factor model (R8/R11/R12): ratio ceiling = LDS B/MFMA; fill needs
// >=8 waves/CU in 4-wave blocks (2-wave blocks underfill: R12 = 77% fill).
// This geometry: 96 KB reads + 48 KB writes per 256 MFMA = 576 B/MFMA ->
// ~54% ceiling. BK=64 (128-B rows) is structurally required: 64-B rows have
// bank = f(chunk) only (row stride == 0 mod 32 banks) -> unavoidable 4-way
// conflicts (the R9/R10 6.3M mystery). 128-B rows + 8-chunk XOR -> 2-way,
// free, measured 0. Single-buffer vmcnt(0) drain; 48 KB LDS; grid 512 ->
// 2 blocks/CU = 8 waves/CU.
template <typename OutT>
__global__ __launch_bounds__(256, 2) void k_gemmT(const u16* __restrict__ A,
                                                  const u16* __restrict__ B,
                                                  OutT* __restrict__ C,
                                                  int M, int N, int K) {
  __shared__ u16 sA[128 * 64];   // 16 KB
  __shared__ u16 sB[256 * 64];   // 32 KB
  const int tid = threadIdx.x;
  const int lane = tid & 63;
  const int w = tid >> 6;        // wave = n-quadrant (0..3)
  const int l15 = lane & 15;
  const int lg = lane >> 4;
  const int sw = l15 & 7;

  const int gx = gridDim.x;              // N / 256
  const int nwg = gx * gridDim.y;
  const int flat = blockIdx.y * gx + blockIdx.x;
  const int tile = (flat & 7) * (nwg >> 3) + (flat >> 3);
  const long m0 = (long)(tile / gx) * 128;
  const long n0 = (long)(tile % gx) * 256;

  const u16* Abase = A + m0 * K;
  const u16* Bbase = B + n0 * K;

  // A: 1024 16B chunks (4/thread); B: 2048 chunks (8/thread). 128-B rows,
  // src chunk = chs ^ (row&7), LDS dst linear (rule 21).
  int aOff[4], aDst[4], bOff[8], bDst[8];
#pragma unroll
  for (int i = 0; i < 4; ++i) {
    const int c = tid + i * 256;
    const int row = c >> 3, chs = c & 7;
    aOff[i] = row * K + (chs ^ (row & 7)) * 8;
    aDst[i] = c * 8;
  }
#pragma unroll
  for (int i = 0; i < 8; ++i) {
    const int c = tid + i * 256;
    const int row = c >> 3, chs = c & 7;
    bOff[i] = row * K + (chs ^ (row & 7)) * 8;
    bDst[i] = c * 8;
  }

  f32x4 acc[8][4];
  const f32x4 z4 = {0.f, 0.f, 0.f, 0.f};
#pragma unroll
  for (int i = 0; i < 8; ++i)
#pragma unroll
    for (int j = 0; j < 4; ++j) acc[i][j] = z4;

  const int akc0 = (lg ^ sw) * 8;
  const int akc1 = ((4 + lg) ^ sw) * 8;
  const int brow0 = w * 64;

  const int NT = K >> 6;

  for (int t = 0; t < NT; ++t) {
#pragma unroll
    for (int i = 0; i < 4; ++i)
      gload_lds16(Abase + aOff[i] + t * 64, &sA[aDst[i]]);
#pragma unroll
    for (int i = 0; i < 8; ++i)
      gload_lds16(Bbase + bOff[i] + t * 64, &sB[bDst[i]]);
    wait_vm<0>();
    __builtin_amdgcn_sched_barrier(0);
    __builtin_amdgcn_s_barrier();
    __builtin_amdgcn_sched_barrier(0);

#pragma unroll
    for (int kk = 0; kk < 2; ++kk) {
      const int akc = (kk == 0) ? akc0 : akc1;
      short8 afk[8], bfk[4];
#pragma unroll
      for (int i = 0; i < 8; ++i)
        afk[i] = *(const short8*)&sA[(i * 16 + l15) * 64 + akc];
#pragma unroll
      for (int j = 0; j < 4; ++j)
        bfk[j] = *(const short8*)&sB[(brow0 + j * 16 + l15) * 64 + akc];
      __builtin_amdgcn_s_setprio(1);
#pragma unroll
      for (int i = 0; i < 8; ++i)
#pragma unroll
        for (int j = 0; j < 4; ++j)
          acc[i][j] = __builtin_amdgcn_mfma_f32_16x16x32_bf16(
              afk[i], bfk[j], acc[i][j], 0, 0, 0);
      __builtin_amdgcn_s_setprio(0);
    }
    __builtin_amdgcn_s_barrier();
    __builtin_amdgcn_sched_barrier(0);
  }

#pragma unroll
  for (int i = 0; i < 8; ++i)
#pragma unroll
    for (int j = 0; j < 4; ++j)
#pragma unroll
      for (int r = 0; r < 4; ++r) {
        long row = m0 + i * 16 + lg * 4 + r;
        long col = n0 + w * 64 + j * 16 + l15;
        store_c(C, row * (long)N + col, acc[i][j][r]);
      }
}

// ---- GEMM (round-11 structure, kept for Wo) : 128x128, 4 waves, 4/CU -------
template <typename OutT>
__global__ __launch_bounds__(256, 4) void k_gemmS(const u16* __restrict__ A,
                                                  const u16* __restrict__ B,
                                                  OutT* __restrict__ C,
                                                  int M, int N, int K) {
  __shared__ u16 sA[128 * 64];
  __shared__ u16 sB[128 * 64];
  const int tid = threadIdx.x;
  const int lane = tid & 63;
  const int w = tid >> 6;
  const int l15 = lane & 15;
  const int lg = lane >> 4;
  const int wm = w >> 1;
  const int wn = w & 1;
  const int sw = l15 & 7;

  const int gx = gridDim.x;
  const int nwg = gx * gridDim.y;
  const int flat = blockIdx.y * gx + blockIdx.x;
  const int tile = (flat & 7) * (nwg >> 3) + (flat >> 3);
  const long m0 = (long)(tile / gx) * 128;
  const long n0 = (long)(tile % gx) * 128;

  const u16* Abase = A + m0 * K;
  const u16* Bbase = B + n0 * K;

  int aOff[4], dstOff[4];
#pragma unroll
  for (int i = 0; i < 4; ++i) {
    const int c = tid + i * 256;
    const int row = c >> 3, chs = c & 7;
    aOff[i] = row * K + (chs ^ (row & 7)) * 8;
    dstOff[i] = c * 8;
  }

  f32x4 acc[4][4];
  const f32x4 z4 = {0.f, 0.f, 0.f, 0.f};
#pragma unroll
  for (int i = 0; i < 4; ++i)
#pragma unroll
    for (int j = 0; j < 4; ++j) acc[i][j] = z4;

  const int arow = (wm * 64 + l15) * 64;
  const int brow = (wn * 64 + l15) * 64;
  const int akc0 = (lg ^ sw) * 8;
  const int akc1 = ((4 + lg) ^ sw) * 8;

  const int NT = K >> 6;

  for (int t = 0; t < NT; ++t) {
#pragma unroll
    for (int i = 0; i < 4; ++i)
      gload_lds16(Abase + aOff[i] + t * 64, &sA[dstOff[i]]);
#pragma unroll
    for (int i = 0; i < 4; ++i)
      gload_lds16(Bbase + aOff[i] + t * 64, &sB[dstOff[i]]);
    wait_vm<0>();
    __builtin_amdgcn_sched_barrier(0);
    __builtin_amdgcn_s_barrier();
    __builtin_amdgcn_sched_barrier(0);

#pragma unroll
    for (int kk = 0; kk < 2; ++kk) {
      const int akc = (kk == 0) ? akc0 : akc1;
      short8 afk[4], bfk[4];
#pragma unroll
      for (int i = 0; i < 4; ++i)
        afk[i] = *(const short8*)&sA[arow + i * 16 * 64 + akc];
#pragma unroll
      for (int j = 0; j < 4; ++j)
        bfk[j] = *(const short8*)&sB[brow + j * 16 * 64 + akc];
      __builtin_amdgcn_s_setprio(1);
#pragma unroll
      for (int i = 0; i < 4; ++i)
#pragma unroll
        for (int j = 0; j < 4; ++j)
          acc[i][j] = __builtin_amdgcn_mfma_f32_16x16x32_bf16(
              afk[i], bfk[j], acc[i][j], 0, 0, 0);
      __builtin_amdgcn_s_setprio(0);
    }
    __builtin_amdgcn_s_barrier();
    __builtin_amdgcn_sched_barrier(0);
  }

#pragma unroll
  for (int i = 0; i < 4; ++i)
#pragma unroll
    for (int j = 0; j < 4; ++j)
#pragma unroll
      for (int r = 0; r < 4; ++r) {
        long row = m0 + wm * 64 + i * 16 + lg * 4 + r;
        long col = n0 + wn * 64 + j * 16 + l15;
        store_c(C, row * (long)N + col, acc[i][j][r]);
      }
}

// ---------------- RMSNorm + RoPE (in place on fused QKV, bf16) ----------------
__global__ __launch_bounds__(256) void k_normrope(u16* __restrict__ QKV,
                                                  const float* __restrict__ cosb,
                                                  const float* __restrict__ sinb,
                                                  const float* __restrict__ qw,
                                                  const float* __restrict__ kw) {
  const int lane = threadIdx.x & 63;
  const int w = threadIdx.x >> 6;
  int row = blockIdx.x * 4 + w;
  const int nQ = BATCH * S_LEN * NH;
  u16* p;
  const float* nw;
  int tok;
  float sc;
  if (row < nQ) {
    tok = row >> 4;
    int h = row & 15;
    p = QKV + (long)tok * QKVW + h * HD;
    nw = qw;
    sc = SCALE;
  } else {
    int r2 = row - nQ;
    tok = r2 >> 3;
    int h = r2 & 7;
    p = QKV + (long)tok * QKVW + 2048 + h * HD;
    nw = kw;
    sc = 1.0f;
  }
  float x0 = b2f(p[lane]);
  float x1 = b2f(p[lane + 64]);
  float ss = x0 * x0 + x1 * x1;
#pragma unroll
  for (int mk = 1; mk < 64; mk <<= 1) ss += __shfl_xor(ss, mk, 64);
  float rinv = rsqrtf(ss * (1.0f / 128.0f) + 1e-6f);
  float y0 = x0 * rinv * nw[lane];
  float y1 = x1 * rinv * nw[lane + 64];
  const float* cp = cosb + (long)tok * HD;
  const float* sp = sinb + (long)tok * HD;
  float o0 = (y0 * cp[lane] - y1 * sp[lane]) * sc;
  float o1 = (y1 * cp[lane + 64] + y0 * sp[lane + 64]) * sc;
  p[lane] = f2b(o0);
  p[lane + 64] = f2b(o1);
}

// ---------------- Flash attention (unchanged) ----------------
__global__ __launch_bounds__(256, 2) void k_attn(const u16* __restrict__ QKV,
                                                 u16* __restrict__ AO) {
  __shared__ u16 sK[64 * 128];
  __shared__ u16 sVT[64 * 128];
  const int tid = threadIdx.x;
  const int lane = tid & 63;
  const int l31 = lane & 31;
  const int hi = lane >> 5;
  const int w = tid >> 6;
  const int q0 = blockIdx.x * 128;
  const int h = blockIdx.y;
  const int b = blockIdx.z;
  const int kvh = h >> 1;
  const int qw0 = q0 + w * 32;
  const int iq = qw0 + l31;

  const long tokbase = (long)b * S_LEN;
  const u16* Qrow = QKV + (tokbase + qw0 + l31) * QKVW + h * HD;
  short8 qf[8];
#pragma unroll
  for (int dt = 0; dt < 8; ++dt) qf[dt] = *(const short8*)(Qrow + dt * 16 + hi * 8);

  f32x16 o[4];
#pragma unroll
  for (int n = 0; n < 4; ++n)
#pragma unroll
    for (int r = 0; r < 16; ++r) o[n][r] = 0.f;
  float m = 0.f, lsum = 0.f;

  const u16* Kbase = QKV + tokbase * QKVW + 2048 + kvh * HD;
  const u16* Vbase = QKV + tokbase * QKVW + 3072 + kvh * HD;

  int kc_row[4], kc_off[4];
  u16* kc_dst[4];
#pragma unroll
  for (int i = 0; i < 4; ++i) {
    const int c = tid + 256 * i;
    kc_row[i] = c >> 4;
    kc_off[i] = (((c & 15) ^ ((c >> 4) & 7))) * 8;
    kc_dst[i] = &sK[c * 8];
  }
  const int rp = tid & 31;
  const int dc0 = tid >> 5;
  const int rg_st = rp >> 2;

  int t_lo = q0 - (WINDOW - 1);
  t_lo = (t_lo < 0 ? 0 : t_lo) >> 6;
  const int t_hi = (q0 + 127) >> 6;

  for (int t = t_lo; t <= t_hi; ++t) {
    const int kv0 = t << 6;
#pragma unroll
    for (int i = 0; i < 4; ++i)
      gload_lds16(Kbase + (long)(kv0 + kc_row[i]) * QKVW + kc_off[i], kc_dst[i]);
#pragma unroll
    for (int i = 0; i < 2; ++i) {
      const int dc = dc0 + i * 8;
      const u16* vp = Vbase + (long)(kv0 + 2 * rp) * QKVW + dc * 8;
      short8 v0 = *(const short8*)vp;
      short8 v1 = *(const short8*)(vp + QKVW);
#pragma unroll
      for (int e = 0; e < 8; ++e) {
        const int d = dc * 8 + e;
        const int unit = d * 8 + (rg_st ^ (d & 7));
        ((u32*)sVT)[unit * 4 + (rp & 3)] = (u32)(u16)v0[e] | ((u32)(u16)v1[e] << 16);
      }
    }
    __syncthreads();

    const bool skipw = (kv0 > qw0 + 31) || (kv0 + 63 < qw0 - (WINDOW - 1));
    if (!skipw) {
      const bool full = (kv0 + 63 <= qw0) && ((qw0 + 31) - kv0 < WINDOW);
      f32x16 s0, s1;
#pragma unroll
      for (int r = 0; r < 16; ++r) { s0[r] = 0.f; s1[r] = 0.f; }
      const int rsw = l31 & 7;
#pragma unroll
      for (int dt = 0; dt < 8; ++dt) {
        const int ch = hi + 2 * dt;
        const short8 kf0 = *(const short8*)&sK[(l31 * 16 + (ch ^ rsw)) * 8];
        s0 = __builtin_amdgcn_mfma_f32_32x32x16_bf16(kf0, qf[dt], s0, 0, 0, 0);
        const short8 kf1 = *(const short8*)&sK[((l31 + 32) * 16 + (ch ^ rsw)) * 8];
        s1 = __builtin_amdgcn_mfma_f32_32x32x16_bf16(kf1, qf[dt], s1, 0, 0, 0);
      }
      float p[32];
#pragma unroll
      for (int r = 0; r < 16; ++r) { p[r] = s0[r]; p[16 + r] = s1[r]; }
      if (!full) {
#pragma unroll
        for (int r = 0; r < 32; ++r) {
          const int kk = kv0 + (r >> 4) * 32 + 4 * hi + (r & 3) + 8 * ((r >> 2) & 3);
          p[r] = ((u32)(iq - kk) < (u32)WINDOW) ? p[r] : -3.0e38f;
        }
      }
      float tm = p[0];
#pragma unroll
      for (int r = 1; r < 32; ++r) tm = fmaxf(tm, p[r]);
      tm = fmaxf(tm, __shfl_xor(tm, 32, 64));
      const float mn = fmaxf(m, tm);
      const float al = __expf(m - mn);
      m = mn;
      float rs = 0.f;
#pragma unroll
      for (int r = 0; r < 32; ++r) { p[r] = __expf(p[r] - mn); rs += p[r]; }
      rs += __shfl_xor(rs, 32, 64);
      lsum = lsum * al + rs;
#pragma unroll
      for (int n = 0; n < 4; ++n)
#pragma unroll
        for (int r = 0; r < 16; ++r) o[n][r] *= al;

      short8 pf[4];
#pragma unroll
      for (int ks = 0; ks < 4; ++ks) {
        const int bb = (ks >> 1) * 16 + (ks & 1) * 8;
        u32 a0 = pk_bf16(p[bb + 0], p[bb + 1]);
        u32 b0 = pk_bf16(p[bb + 4], p[bb + 5]);
        u32 a1 = pk_bf16(p[bb + 2], p[bb + 3]);
        u32 b1 = pk_bf16(p[bb + 6], p[bb + 7]);
        asm volatile("v_permlane32_swap_b32 %0, %1" : "+v"(a0), "+v"(b0));
        asm volatile("v_permlane32_swap_b32 %0, %1" : "+v"(a1), "+v"(b1));
        union { u32 u[4]; short8 s; } uu;
        uu.u[0] = a0; uu.u[1] = a1; uu.u[2] = b0; uu.u[3] = b1;
        pf[ks] = uu.s;
      }
#pragma unroll
      for (int dt = 0; dt < 4; ++dt) {
        const int d = l31 + 32 * dt;
        const int dsw = d & 7;
#pragma unroll
        for (int ks = 0; ks < 4; ++ks) {
          const int rg = ks * 2 + hi;
          const short8 vf = *(const short8*)&sVT[(d * 8 + (rg ^ dsw)) * 8];
          o[dt] = __builtin_amdgcn_mfma_f32_32x32x16_bf16(vf, pf[ks], o[dt], 0, 0, 0);
        }
      }
    }
    __syncthreads();
  }

  __syncthreads();
  float* R = ((float*)sK) + w * 1024;
  const float rl = 1.0f / lsum;
  const int half = hi;
#pragma unroll
  for (int dt = 0; dt < 4; ++dt) {
#pragma unroll
    for (int r = 0; r < 16; ++r) {
      const int dp = 4 * hi + (r & 3) + 8 * (r >> 2);
      R[dp * 32 + (l31 ^ (4 * (dp & 7)))] = o[dt][r] * rl;
    }
    __syncthreads();
    union { u16 hh[16]; short8 s[2]; } U;
#pragma unroll
    for (int j = 0; j < 16; ++j) {
      const int dp = half * 16 + j;
      U.hh[j] = f2b(R[dp * 32 + (l31 ^ (4 * (dp & 7)))]);
    }
    u16* dst = AO + (tokbase + q0 + w * 32 + l31) * (NH * HD) + h * HD + dt * 32 + half * 16;
    *(short8*)dst = U.s[0];
    *(short8*)(dst + 8) = U.s[1];
    __syncthreads();
  }
}

// ---------------- launch ----------------
extern "C" void kernel_launch(void* const* d_in, const int* in_sizes, int n_in,
                              void* d_out, int out_size, void* d_ws, size_t ws_size,
                              hipStream_t stream) {
  const float* hs   = (const float*)d_in[0];
  const float* cosb = (const float*)d_in[1];
  const float* sinb = (const float*)d_in[2];
  const float* Wq   = (const float*)d_in[3];
  const float* Wk   = (const float*)d_in[4];
  const float* Wv   = (const float*)d_in[5];
  const float* Wo   = (const float*)d_in[6];
  const float* qw   = (const float*)d_in[7];
  const float* kw   = (const float*)d_in[8];
  float* out = (float*)d_out;

  const long SZ_X  = (long)BATCH * S_LEN * HID;
  const long SZ_WQ = (long)NH * HD * HID;
  const long SZ_WK = (long)NKV * HD * HID;
  u16* Xb   = (u16*)d_ws;
  u16* Wqb  = Xb + SZ_X;
  u16* Wkb  = Wqb + SZ_WQ;
  u16* Wvb  = Wkb + SZ_WK;
  u16* Wob  = Wvb + SZ_WK;
  u16* QKVb = Wob + SZ_WQ;
  u16* AOb  = QKVb + (long)BATCH * S_LEN * QKVW;

  k_conv5<<<2048, 256, 0, stream>>>(hs, Wq, Wk, Wv, Wo, Xb);

  // fused QKV projection: 4096 x 4096 x 2048, 128x256 tiles -> 512 blocks
  k_gemmT<u16><<<dim3(16, 32), 256, 0, stream>>>(
      Xb, Wqb, QKVb, BATCH * S_LEN, QKVW, HID);

  k_normrope<<<(BATCH * S_LEN * (NH + NKV)) / 4, 256, 0, stream>>>(QKVb, cosb, sinb, qw, kw);

  k_attn<<<dim3(S_LEN / 128, NH, BATCH), 256, 0, stream>>>(QKVb, AOb);

  // output projection: 4096 x 2048 x 2048, 512 blocks (round-11 kernel)
  k_gemmS<float><<<dim3(16, 32), 256, 0, stream>>>(
      AOb, Wob, out, BATCH * S_LEN, HID, HID);
}